// Round 20
// baseline (24.820 us; speedup 1.0000x reference)
//
#include <hip/hip_runtime.h>
#include <math.h>

constexpr int Bb = 4, Cc = 64, Hh = 256, Ww = 256;
constexpr int RR = 4;             // output rows per block (amp 1.5x)
constexpr int NSTRIP = Hh / RR;   // 64
constexpr int NBLK = Bb * NSTRIP; // 256 entropy blocks = 1 per CU
constexpr int NPX = Bb * Hh * Ww; // 262144 output pixels
constexpr int NPX4 = NPX / 4;

#define LOG2E 1.44269504088896340736f

__device__ __forceinline__ unsigned int fenc(float f) {
  unsigned int u = __float_as_uint(f);
  return (u & 0x80000000u) ? ~u : (u | 0x80000000u);
}
__device__ __forceinline__ float fdec(unsigned int k) {
  return __uint_as_float((k & 0x80000000u) ? (k ^ 0x80000000u) : ~k);
}

// Rescaled entropy (affine-invariant under the final min/max normalize):
//   e' = entropy/ln2 = log2(s) - (sum u*a)/s,  u = v*log2e, a = 2^u = e^v,
//   s = 3x3 box of a. u is the exp2 input, reused for the b-product — the
//   LN2 multiply in the old form is gone.
//
// CS=1 full-channel geometry (r19, best): block (64,16) = 16 waves; lane =
// 4 cols (float4, full 256-col row; halos are image edges = constants);
// ty = 4 channels (rolled cc loop, streaming ring body). RR=4 rows/block.
// Grid = 256 blocks = exactly 1 block/CU (residency guaranteed).
// Interior strips (62/64) take an unconditional-load path (no row checks).
// Two-stage LDS reduce: 16 groups -> 4 -> 1 (serial depth 16 -> 8).
// FB=0: block min/max -> pm[bx] non-atomic. FB=1: atomic fallback.
// NOTE: plain __launch_bounds__(1024) — min-waves hints spill (r6/r7).
// All acc indices compile-time (r15: runtime idx -> scratch).
template <int FB>
__global__ __launch_bounds__(1024) void entropy_kernel(const float* __restrict__ x,
                                                       float* __restrict__ e,
                                                       float* __restrict__ pm,
                                                       unsigned int* __restrict__ stats) {
  const int bx = blockIdx.x;
  const int strip = bx & (NSTRIP - 1);
  const int b = bx >> 6;
  const int r0 = strip * RR;
  const int tx = threadIdx.x;   // 0..63
  const int ty = threadIdx.y;   // 0..15
  const int w0 = tx * 4;

  const size_t planeStride = (size_t)Hh * Ww;
  const float* xb = x + ((size_t)b * Cc + ty * 4) * planeStride + w0;
  const bool interior = (strip != 0) && (strip != NSTRIP - 1);

  float acc[RR][4];
#pragma unroll
  for (int o = 0; o < RR; ++o)
#pragma unroll
    for (int i = 0; i < 4; ++i) acc[o][i] = 0.f;

  // Row-processing macro body (shared by both paths). v4 is the loaded row.
#define PROCESS_ROW(J, V4)                                                    \
  {                                                                           \
    const float* vp = &(V4).x;                                                \
    float u[4], a[4], bb4[4];                                                 \
    _Pragma("unroll")                                                         \
    for (int i = 0; i < 4; ++i) {                                             \
      u[i] = vp[i] * LOG2E;                                                   \
      a[i] = __builtin_amdgcn_exp2f(u[i]);                                    \
      bb4[i] = u[i] * a[i];                                                   \
    }                                                                         \
    float la = __shfl_up(a[3], 1, 64);                                        \
    float lb = __shfl_up(bb4[3], 1, 64);                                      \
    float ra = __shfl_down(a[0], 1, 64);                                      \
    float rb = __shfl_down(bb4[0], 1, 64);                                    \
    la = (tx == 0) ? 1.f : la;   lb = (tx == 0) ? 0.f : lb;                   \
    ra = (tx == 63) ? 1.f : ra;  rb = (tx == 63) ? 0.f : rb;                  \
    const int s0 = (J) % 3;                                                   \
    {                                                                         \
      float t01 = a[0] + a[1], t23 = a[2] + a[3];                             \
      ha[s0][0] = la + t01;                                                   \
      ha[s0][1] = t01 + a[2];                                                 \
      ha[s0][2] = a[1] + t23;                                                 \
      ha[s0][3] = t23 + ra;                                                   \
    }                                                                         \
    {                                                                         \
      float t01 = bb4[0] + bb4[1], t23 = bb4[2] + bb4[3];                     \
      hb[s0][0] = lb + t01;                                                   \
      hb[s0][1] = t01 + bb4[2];                                               \
      hb[s0][2] = bb4[1] + t23;                                               \
      hb[s0][3] = t23 + rb;                                                   \
    }                                                                         \
    if ((J) >= 2) {                                                           \
      const int orow = (J) - 2;                                               \
      _Pragma("unroll")                                                       \
      for (int i = 0; i < 4; ++i) {                                           \
        float s = ha[0][i] + ha[1][i] + ha[2][i];                             \
        float w = hb[0][i] + hb[1][i] + hb[2][i];                             \
        acc[orow][i] += __builtin_amdgcn_logf(s) -                            \
                        w * __builtin_amdgcn_rcpf(s);                         \
      }                                                                       \
    }                                                                         \
  }

  if (interior) {
#pragma unroll 1
    for (int cc = 0; cc < 4; ++cc) {
      const float* plane = xb + (size_t)cc * planeStride;
      float ha[3][4], hb[3][4];
#pragma unroll
      for (int j = 0; j < RR + 2; ++j) {
        float4 v = *reinterpret_cast<const float4*>(
            plane + (size_t)(r0 - 1 + j) * Ww);   // unconditional
        PROCESS_ROW(j, v)
      }
    }
  } else {
#pragma unroll 1
    for (int cc = 0; cc < 4; ++cc) {
      const float* plane = xb + (size_t)cc * planeStride;
      float ha[3][4], hb[3][4];
#pragma unroll
      for (int j = 0; j < RR + 2; ++j) {
        const int row = r0 - 1 + j;
        float4 v = make_float4(0.f, 0.f, 0.f, 0.f);
        if (row >= 0 && row < Hh)
          v = *reinterpret_cast<const float4*>(plane + (size_t)row * Ww);
        PROCESS_ROW(j, v)
      }
    }
  }
#undef PROCESS_ROW

  // Two-stage reduce of the 16 ty channel groups.
  __shared__ float red[16][RR][4][64];   // 64 KiB
  __shared__ float red2[4][RR][4][64];   // 16 KiB (fits: 1 block/CU)
#pragma unroll
  for (int o = 0; o < RR; ++o)
#pragma unroll
    for (int i = 0; i < 4; ++i) red[ty][o][i][tx] = acc[o][i];
  __syncthreads();
  {
    const int o = ty & 3, q = ty >> 2;   // all 16 waves work
#pragma unroll
    for (int i = 0; i < 4; ++i)
      red2[q][o][i][tx] = red[q * 4 + 0][o][i][tx] + red[q * 4 + 1][o][i][tx] +
                          red[q * 4 + 2][o][i][tx] + red[q * 4 + 3][o][i][tx];
  }
  __syncthreads();

  float mn = INFINITY, mx = -INFINITY;
  if (ty < RR) {
    const size_t px = (size_t)(b * Hh + r0 + ty) * Ww + w0;
    float vsum[4];
#pragma unroll
    for (int i = 0; i < 4; ++i)
      vsum[i] = red2[0][ty][i][tx] + red2[1][ty][i][tx] +
                red2[2][ty][i][tx] + red2[3][ty][i][tx];
    *reinterpret_cast<float4*>(e + px) =
        make_float4(vsum[0], vsum[1], vsum[2], vsum[3]);
    mn = fminf(fminf(vsum[0], vsum[1]), fminf(vsum[2], vsum[3]));
    mx = fmaxf(fmaxf(vsum[0], vsum[1]), fmaxf(vsum[2], vsum[3]));
#pragma unroll
    for (int off = 32; off > 0; off >>= 1) {
      mn = fminf(mn, __shfl_down(mn, off, 64));
      mx = fmaxf(mx, __shfl_down(mx, off, 64));
    }
  }
  __shared__ float smn[RR], smx[RR];
  if (ty < RR && tx == 0) { smn[ty] = mn; smx[ty] = mx; }
  __syncthreads();
  if (ty == 0 && tx == 0) {
    mn = fminf(fminf(smn[0], smn[1]), fminf(smn[2], smn[3]));
    mx = fmaxf(fmaxf(smx[0], smx[1]), fmaxf(smx[2], smx[3]));
    if (FB == 0) {
      pm[bx] = mn;           // every slot written -> no init
      pm[NBLK + bx] = mx;
    } else {
      atomicMin(&stats[b], fenc(mn));
      atomicMax(&stats[4 + b], fenc(mx));
    }
  }
}

// Reduce this batch's 64 pm pairs in one wave, then normalize.
__global__ __launch_bounds__(256) void norm_ws(float* __restrict__ e,
                                               const float* __restrict__ pm) {
  const int bx = blockIdx.x;
  const int b = bx >> 6;
  const int lane = threadIdx.x & 63;
  float mn = pm[b * 64 + lane];
  float mx = pm[NBLK + b * 64 + lane];
#pragma unroll
  for (int off = 32; off > 0; off >>= 1) {
    mn = fminf(mn, __shfl_down(mn, off, 64));
    mx = fmaxf(mx, __shfl_down(mx, off, 64));
  }
  mn = __shfl(mn, 0, 64);
  mx = __shfl(mx, 0, 64);
  const float inv = 1.0f / fmaxf(mx - mn, 1e-6f);

  const int t = bx * 256 + threadIdx.x;
  float4 v = reinterpret_cast<float4*>(e)[t];
  v.x = (v.x - mn) * inv;
  v.y = (v.y - mn) * inv;
  v.z = (v.z - mn) * inv;
  v.w = (v.w - mn) * inv;
  reinterpret_cast<float4*>(e)[t] = v;
}

// Fallback normalize from atomic stats.
__global__ __launch_bounds__(256) void norm_atomic(float* __restrict__ e,
                                                   const unsigned int* __restrict__ stats) {
  const int t = blockIdx.x * 256 + threadIdx.x;
  const int b = t >> 14;
  const float mn = fdec(stats[b]);
  const float mx = fdec(stats[4 + b]);
  const float inv = 1.0f / fmaxf(mx - mn, 1e-6f);
  float4 v = reinterpret_cast<float4*>(e)[t];
  v.x = (v.x - mn) * inv;
  v.y = (v.y - mn) * inv;
  v.z = (v.z - mn) * inv;
  v.w = (v.w - mn) * inv;
  reinterpret_cast<float4*>(e)[t] = v;
}

extern "C" void kernel_launch(void* const* d_in, const int* in_sizes, int n_in,
                              void* d_out, int out_size, void* d_ws, size_t ws_size,
                              hipStream_t stream) {
  const float* x = (const float*)d_in[0];
  float* out = (float*)d_out;

  const size_t ws_needed = (size_t)(2 * NBLK) * sizeof(float);  // 2 KB
  if (ws_size >= ws_needed) {
    float* pm = (float*)d_ws;  // [NBLK min][NBLK max]
    entropy_kernel<0><<<dim3(NBLK), dim3(64, 16), 0, stream>>>(x, out, pm, nullptr);
    norm_ws<<<dim3(NPX4 / 256), dim3(256), 0, stream>>>(out, pm);
  } else {
    unsigned int* stats = (unsigned int*)d_ws;  // 8 uints
    hipMemsetAsync(stats, 0xFF, 4 * sizeof(unsigned int), stream);
    hipMemsetAsync(stats + 4, 0x00, 4 * sizeof(unsigned int), stream);
    entropy_kernel<1><<<dim3(NBLK), dim3(64, 16), 0, stream>>>(x, out, nullptr, stats);
    norm_atomic<<<dim3(NPX4 / 256), dim3(256), 0, stream>>>(out, stats);
  }
}